// Round 2
// baseline (631.027 us; speedup 1.0000x reference)
//
#include <hip/hip_runtime.h>

// Modulated deformable conv 3x3, in_ch=out_ch=1, stride=1, pad=1, dil=1.
// B=8, H=W=512 (hardcoded). d_in order: depth, mask(weight), offset, w, b.
// R1: 4 pixels/thread, float4 streaming loads (nontemporal), 4 indep acc chains.

#define KK 9
#define PAD 1
#define H 512
#define W 512
#define HW (H * W)

typedef float f4 __attribute__((ext_vector_type(4)));

__device__ __forceinline__ float bilin(const float* __restrict__ img,
                                       float y, float x) {
    float y0f = floorf(y);
    float x0f = floorf(x);
    int y0 = (int)y0f;
    int x0 = (int)x0f;
    float wy = y - y0f;
    float wx = x - x0f;
    int y1 = y0 + 1;
    int x1 = x0 + 1;

    bool y0i = (y0 >= 0) & (y0 < H);
    bool y1i = (y1 >= 0) & (y1 < H);
    bool x0i = (x0 >= 0) & (x0 < W);
    bool x1i = (x1 >= 0) & (x1 < W);

    int y0c = min(max(y0, 0), H - 1);
    int y1c = min(max(y1, 0), H - 1);
    int x0c = min(max(x0, 0), W - 1);
    int x1c = min(max(x1, 0), W - 1);

    // int indexing -> sgpr-base + vgpr-offset addressing
    float v00 = (y0i & x0i) ? img[y0c * W + x0c] : 0.0f;
    float v01 = (y0i & x1i) ? img[y0c * W + x1c] : 0.0f;
    float v10 = (y1i & x0i) ? img[y1c * W + x0c] : 0.0f;
    float v11 = (y1i & x1i) ? img[y1c * W + x1c] : 0.0f;

    float omwy = 1.0f - wy;
    float omwx = 1.0f - wx;
    return fmaf(v00 * omwy, omwx,
           fmaf(v01 * omwy, wx,
           fmaf(v10 * wy,   omwx, v11 * wy * wx)));
}

__global__ __launch_bounds__(256, 4) void dcn_kernel(
    const float* __restrict__ depth,
    const float* __restrict__ mask,
    const float* __restrict__ offset,
    const float* __restrict__ w9,
    const float* __restrict__ bias,
    float* __restrict__ out) {
    const int t = blockIdx.x * blockDim.x + threadIdx.x;
    const int p = t * 4;                  // first of 4 consecutive pixels
    const int b = blockIdx.y;

    const int y  = p >> 9;                // W = 512
    const int x0 = p & (W - 1);

    const float* __restrict__ img = depth + (long)b * HW;
    const f4* __restrict__ msk = (const f4*)(mask   + (long)b * KK * HW + p);
    const f4* __restrict__ off = (const f4*)(offset + (long)b * 2 * KK * HW + p);

    const float bs = bias[0];
    float acc0 = bs, acc1 = bs, acc2 = bs, acc3 = bs;

    #pragma unroll
    for (int k = 0; k < KK; ++k) {
        const int ky = k / 3;
        const int kx = k - ky * 3;
        // streaming one-touch data: nontemporal to keep depth hot in L1/L2
        f4 dy = __builtin_nontemporal_load(&off[(2 * k)     * (HW / 4)]);
        f4 dx = __builtin_nontemporal_load(&off[(2 * k + 1) * (HW / 4)]);
        f4 m  = __builtin_nontemporal_load(&msk[k * (HW / 4)]);
        const float wk = w9[k];
        const float syb = (float)(y - PAD + ky);
        const float sxb = (float)(x0 - PAD + kx);

        acc0 = fmaf(bilin(img, syb + dy.x, sxb + 0.0f + dx.x), m.x * wk, acc0);
        acc1 = fmaf(bilin(img, syb + dy.y, sxb + 1.0f + dx.y), m.y * wk, acc1);
        acc2 = fmaf(bilin(img, syb + dy.z, sxb + 2.0f + dx.z), m.z * wk, acc2);
        acc3 = fmaf(bilin(img, syb + dy.w, sxb + 3.0f + dx.w), m.w * wk, acc3);
    }

    f4 r;
    r.x = acc0; r.y = acc1; r.z = acc2; r.w = acc3;
    __builtin_nontemporal_store(r, (f4*)(out + (long)b * HW + p));
}

extern "C" void kernel_launch(void* const* d_in, const int* in_sizes, int n_in,
                              void* d_out, int out_size, void* d_ws, size_t ws_size,
                              hipStream_t stream) {
    const float* depth  = (const float*)d_in[0];
    const float* mask   = (const float*)d_in[1];   // reference's "weight" arg = modulation mask
    const float* offset = (const float*)d_in[2];
    const float* w9     = (const float*)d_in[3];
    const float* bias   = (const float*)d_in[4];
    float* out = (float*)d_out;

    const int B = in_sizes[0] / HW;   // = 8

    dim3 block(256);
    dim3 grid(HW / (256 * 4), B);     // 512*512 divisible by 1024
    dcn_kernel<<<grid, block, 0, stream>>>(depth, mask, offset, w9, bias, out);
}

// Round 3
// 281.939 us; speedup vs baseline: 2.2382x; 2.2382x over previous
//
#include <hip/hip_runtime.h>

// Modulated deformable conv 3x3, in_ch=out_ch=1, stride=1, pad=1, dil=1.
// B=8, H=W=512 (hardcoded). d_in order: depth, mask(weight), offset, w, b.
// R2: LDS-staged depth tile (64x16 out, halo 8) -> bilinear corners are LDS
// reads with zero bounds logic; global-gather fallback only for |off|>=~7
// (p ~ 2.6e-12 per sample). No launch_bounds, no nontemporal (R1 post-mortem:
// VGPR cap + giant unrolled live ranges caused ~860 MB of scratch spill traffic).

#define KK 9
#define PAD 1
#define H 512
#define W 512
#define HW (H * W)

#define TX 64
#define TY 16
#define HALO 8
#define LW (TX + 2 * HALO)   // 80
#define LH (TY + 2 * HALO)   // 32

__device__ __forceinline__ float bilin_global(const float* __restrict__ img,
                                              float y, float x) {
    float y0f = floorf(y);
    float x0f = floorf(x);
    int y0 = (int)y0f;
    int x0 = (int)x0f;
    float wy = y - y0f;
    float wx = x - x0f;
    int y1 = y0 + 1;
    int x1 = x0 + 1;

    bool y0i = (y0 >= 0) & (y0 < H);
    bool y1i = (y1 >= 0) & (y1 < H);
    bool x0i = (x0 >= 0) & (x0 < W);
    bool x1i = (x1 >= 0) & (x1 < W);

    int y0c = min(max(y0, 0), H - 1);
    int y1c = min(max(y1, 0), H - 1);
    int x0c = min(max(x0, 0), W - 1);
    int x1c = min(max(x1, 0), W - 1);

    float v00 = (y0i & x0i) ? img[y0c * W + x0c] : 0.0f;
    float v01 = (y0i & x1i) ? img[y0c * W + x1c] : 0.0f;
    float v10 = (y1i & x0i) ? img[y1c * W + x0c] : 0.0f;
    float v11 = (y1i & x1i) ? img[y1c * W + x1c] : 0.0f;

    float omwy = 1.0f - wy;
    float omwx = 1.0f - wx;
    return fmaf(v00 * omwy, omwx,
           fmaf(v01 * omwy, wx,
           fmaf(v10 * wy,   omwx, v11 * wy * wx)));
}

__global__ void dcn_kernel(
    const float* __restrict__ depth,
    const float* __restrict__ mask,
    const float* __restrict__ offset,
    const float* __restrict__ w9,
    const float* __restrict__ bias,
    float* __restrict__ out) {
    __shared__ float S[LH * LW];

    const int b  = blockIdx.z;
    const int bx = blockIdx.x;
    const int by = blockIdx.y;
    const int tX0 = bx * TX - HALO;
    const int tY0 = by * TY - HALO;

    const float* __restrict__ img = depth + (long)b * HW;

    // --- stage depth tile (+halo) into LDS; out-of-image cells = 0 ---
    for (int i = threadIdx.x; i < LH * LW; i += 256) {
        const int ly = i / LW;              // const divisor -> magic mul
        const int lx = i - ly * LW;
        const int gy = tY0 + ly;
        const int gx = tX0 + lx;
        float v = 0.0f;
        if (((unsigned)gy < (unsigned)H) & ((unsigned)gx < (unsigned)W))
            v = img[gy * W + gx];
        S[i] = v;
    }
    __syncthreads();

    // --- each thread: 4 row-strided pixels (consecutive lanes -> consecutive x) ---
    const int lx  = threadIdx.x & 63;       // 0..63
    const int lyb = threadIdx.x >> 6;       // 0..3
    const int tx  = bx * TX + lx;

    const float* __restrict__ msk = mask   + ((long)b * KK)     * HW;
    const float* __restrict__ off = offset + ((long)b * 2 * KK) * HW;

    const float bs = bias[0];
    float acc[4] = {bs, bs, bs, bs};
    int ty[4];
    #pragma unroll
    for (int i = 0; i < 4; ++i) ty[i] = by * TY + lyb + 4 * i;

    #pragma unroll
    for (int k = 0; k < KK; ++k) {
        const int ky = k / 3;
        const int kx = k - ky * 3;
        const float wk = w9[k];

        #pragma unroll
        for (int i = 0; i < 4; ++i) {
            const int pix = ty[i] * W + tx;
            const float dy = off[(2 * k) * HW + pix];
            const float dx = off[(2 * k + 1) * HW + pix];
            const float m  = msk[k * HW + pix];

            const float sy = (float)(ty[i] - PAD + ky) + dy;
            const float sx = (float)(tx    - PAD + kx) + dx;

            const float y0f = floorf(sy);
            const float x0f = floorf(sx);
            const float wy = sy - y0f;
            const float wx = sx - x0f;
            const int y0 = (int)y0f;
            const int x0 = (int)x0f;
            const int ly0 = y0 - tY0;
            const int lx0 = x0 - tX0;

            float v;
            if (((unsigned)ly0 < (unsigned)(LH - 1)) &
                ((unsigned)lx0 < (unsigned)(LW - 1))) {
                // fast path: all 4 corners inside LDS tile; OOB-image cells are 0
                const int s = ly0 * LW + lx0;
                const float v00 = S[s];
                const float v01 = S[s + 1];
                const float v10 = S[s + LW];
                const float v11 = S[s + LW + 1];
                const float omwy = 1.0f - wy;
                const float omwx = 1.0f - wx;
                v = fmaf(v00 * omwy, omwx,
                    fmaf(v01 * omwy, wx,
                    fmaf(v10 * wy,   omwx, v11 * wy * wx)));
            } else {
                // ~never taken (|offset| >= ~7): correct global fallback
                v = bilin_global(img, sy, sx);
            }
            acc[i] = fmaf(v, m * wk, acc[i]);
        }
    }

    float* __restrict__ o = out + (long)b * HW;
    #pragma unroll
    for (int i = 0; i < 4; ++i)
        o[ty[i] * W + tx] = acc[i];
}

extern "C" void kernel_launch(void* const* d_in, const int* in_sizes, int n_in,
                              void* d_out, int out_size, void* d_ws, size_t ws_size,
                              hipStream_t stream) {
    const float* depth  = (const float*)d_in[0];
    const float* mask   = (const float*)d_in[1];   // reference's "weight" arg = modulation mask
    const float* offset = (const float*)d_in[2];
    const float* w9     = (const float*)d_in[3];
    const float* bias   = (const float*)d_in[4];
    float* out = (float*)d_out;

    const int B = in_sizes[0] / HW;   // = 8

    dim3 block(256);
    dim3 grid(W / TX, H / TY, B);     // (8, 32, 8)
    dcn_kernel<<<grid, block, 0, stream>>>(depth, mask, offset, w9, bias, out);
}

// Round 4
// 279.367 us; speedup vs baseline: 2.2588x; 1.0092x over previous
//
#include <hip/hip_runtime.h>

// Modulated deformable conv 3x3, in_ch=out_ch=1, stride=1, pad=1, dil=1.
// B=8, H=W=512. d_in order: depth, mask(weight), offset, w, b.
// R4: latency-bound fix. 4 pixels/thread as 2x-consecutive x 2y-strided ->
// all mask/offset streaming loads are dwordx2 (half the VMEM instrs, 512B/instr).
// launch_bounds(256,4) = 128 VGPR cap; k-loop unroll 3 bounds live loads
// (~36 VGPRs of streaming data in flight) -- avoids R1's scratch-spill blowup.
// LDS depth tile (64x16 out + halo 8) unchanged from R3 (verified correct).

#define KK 9
#define PAD 1
#define H 512
#define W 512
#define HW (H * W)

#define TX 64
#define TY 16
#define HALO 8
#define LW (TX + 2 * HALO)   // 80
#define LH (TY + 2 * HALO)   // 32

typedef float f2 __attribute__((ext_vector_type(2)));

__device__ __forceinline__ float bilin_global(const float* __restrict__ img,
                                              float y, float x) {
    float y0f = floorf(y);
    float x0f = floorf(x);
    int y0 = (int)y0f;
    int x0 = (int)x0f;
    float wy = y - y0f;
    float wx = x - x0f;
    int y1 = y0 + 1;
    int x1 = x0 + 1;

    bool y0i = (y0 >= 0) & (y0 < H);
    bool y1i = (y1 >= 0) & (y1 < H);
    bool x0i = (x0 >= 0) & (x0 < W);
    bool x1i = (x1 >= 0) & (x1 < W);

    int y0c = min(max(y0, 0), H - 1);
    int y1c = min(max(y1, 0), H - 1);
    int x0c = min(max(x0, 0), W - 1);
    int x1c = min(max(x1, 0), W - 1);

    float v00 = (y0i & x0i) ? img[y0c * W + x0c] : 0.0f;
    float v01 = (y0i & x1i) ? img[y0c * W + x1c] : 0.0f;
    float v10 = (y1i & x0i) ? img[y1c * W + x0c] : 0.0f;
    float v11 = (y1i & x1i) ? img[y1c * W + x1c] : 0.0f;

    float omwy = 1.0f - wy;
    float omwx = 1.0f - wx;
    return fmaf(v00 * omwy, omwx,
           fmaf(v01 * omwy, wx,
           fmaf(v10 * wy,   omwx, v11 * wy * wx)));
}

__device__ __forceinline__ float sample_tile(const float* __restrict__ S,
                                             const float* __restrict__ img,
                                             int tY0, int tX0,
                                             float sy, float sx) {
    const float y0f = floorf(sy);
    const float x0f = floorf(sx);
    const float wy = sy - y0f;
    const float wx = sx - x0f;
    const int ly0 = (int)y0f - tY0;
    const int lx0 = (int)x0f - tX0;

    if (((unsigned)ly0 < (unsigned)(LH - 1)) &
        ((unsigned)lx0 < (unsigned)(LW - 1))) {
        const int s = ly0 * LW + lx0;
        const float v00 = S[s];
        const float v01 = S[s + 1];
        const float v10 = S[s + LW];
        const float v11 = S[s + LW + 1];
        const float omwy = 1.0f - wy;
        const float omwx = 1.0f - wx;
        return fmaf(v00 * omwy, omwx,
               fmaf(v01 * omwy, wx,
               fmaf(v10 * wy,   omwx, v11 * wy * wx)));
    }
    // ~never taken (|offset| >= ~7, p ~ 2.6e-12/sample): correct global fallback
    return bilin_global(img, sy, sx);
}

__global__ __launch_bounds__(256, 4) void dcn_kernel(
    const float* __restrict__ depth,
    const float* __restrict__ mask,
    const float* __restrict__ offset,
    const float* __restrict__ w9,
    const float* __restrict__ bias,
    float* __restrict__ out) {
    __shared__ float S[LH * LW];

    const int b  = blockIdx.z;
    const int bx = blockIdx.x;
    const int by = blockIdx.y;
    const int tX0 = bx * TX - HALO;
    const int tY0 = by * TY - HALO;

    const float* __restrict__ img = depth + (long)b * HW;

    // --- stage depth tile (+halo) into LDS; out-of-image cells = 0 ---
    for (int i = threadIdx.x; i < LH * LW; i += 256) {
        const int ly = i / LW;
        const int lx = i - ly * LW;
        const int gy = tY0 + ly;
        const int gx = tX0 + lx;
        float v = 0.0f;
        if (((unsigned)gy < (unsigned)H) & ((unsigned)gx < (unsigned)W))
            v = img[gy * W + gx];
        S[i] = v;
    }
    __syncthreads();

    // --- 4 pixels/thread: 2 consecutive x (dwordx2 streaming) x 2 strided y ---
    const int xp = threadIdx.x & 31;        // x-pair index 0..31
    const int yr = threadIdx.x >> 5;        // 0..7
    const int tx  = bx * TX + 2 * xp;       // even x
    const int ty0 = by * TY + yr;
    const int ty1 = ty0 + 8;

    const float* __restrict__ msk = mask   + ((long)b * KK)     * HW;
    const float* __restrict__ off = offset + ((long)b * 2 * KK) * HW;

    const float bs = bias[0];
    float a00 = bs, a01 = bs, a10 = bs, a11 = bs;  // [row][xlo/xhi]

    const int pix0 = ty0 * W + tx;
    const int pix1 = ty1 * W + tx;

    #pragma unroll 3
    for (int k = 0; k < KK; ++k) {
        const int ky = k / 3;
        const int kx = k - ky * 3;
        const float wk = w9[k];
        const float syb0 = (float)(ty0 - PAD + ky);
        const float syb1 = (float)(ty1 - PAD + ky);
        const float sxb  = (float)(tx  - PAD + kx);

        const f2 dy0 = *(const f2*)(off + (2 * k) * HW + pix0);
        const f2 dx0 = *(const f2*)(off + (2 * k + 1) * HW + pix0);
        const f2 m0  = *(const f2*)(msk + k * HW + pix0);
        const f2 dy1 = *(const f2*)(off + (2 * k) * HW + pix1);
        const f2 dx1 = *(const f2*)(off + (2 * k + 1) * HW + pix1);
        const f2 m1  = *(const f2*)(msk + k * HW + pix1);

        a00 = fmaf(sample_tile(S, img, tY0, tX0, syb0 + dy0.x, sxb + 0.0f + dx0.x),
                   m0.x * wk, a00);
        a01 = fmaf(sample_tile(S, img, tY0, tX0, syb0 + dy0.y, sxb + 1.0f + dx0.y),
                   m0.y * wk, a01);
        a10 = fmaf(sample_tile(S, img, tY0, tX0, syb1 + dy1.x, sxb + 0.0f + dx1.x),
                   m1.x * wk, a10);
        a11 = fmaf(sample_tile(S, img, tY0, tX0, syb1 + dy1.y, sxb + 1.0f + dx1.y),
                   m1.y * wk, a11);
    }

    float* __restrict__ o = out + (long)b * HW;
    f2 r0; r0.x = a00; r0.y = a01;
    f2 r1; r1.x = a10; r1.y = a11;
    *(f2*)(o + pix0) = r0;
    *(f2*)(o + pix1) = r1;
}

extern "C" void kernel_launch(void* const* d_in, const int* in_sizes, int n_in,
                              void* d_out, int out_size, void* d_ws, size_t ws_size,
                              hipStream_t stream) {
    const float* depth  = (const float*)d_in[0];
    const float* mask   = (const float*)d_in[1];   // reference's "weight" arg = modulation mask
    const float* offset = (const float*)d_in[2];
    const float* w9     = (const float*)d_in[3];
    const float* bias   = (const float*)d_in[4];
    float* out = (float*)d_out;

    const int B = in_sizes[0] / HW;   // = 8

    dim3 block(256);
    dim3 grid(W / TX, H / TY, B);     // (8, 32, 8)
    dcn_kernel<<<grid, block, 0, stream>>>(depth, mask, offset, w9, bias, out);
}

// Round 5
// 277.002 us; speedup vs baseline: 2.2781x; 1.0085x over previous
//
#include <hip/hip_runtime.h>

// Modulated deformable conv 3x3, in_ch=out_ch=1, stride=1, pad=1, dil=1.
// B=8, H=W=512. d_in order: depth, mask(weight), offset, w, b.
// R5: memory-level-parallelism fix. Each thread: 2 consecutive px; ALL 27
// streaming dwordx2 loads (dy,dx,m x 9 taps) issued up front into register
// arrays (54 VGPRs payload), consumed afterwards -> 27 outstanding loads/wave
// vs ~3 in R4 (VGPR_Count=36 showed the compiler never pipelined on its own).
// LDS depth tile 64x8 out + halo 8 (7.7 KB); rare global fallback for |off|>=~7.
// No launch_bounds (R1 post-mortem: VGPR cap + big live ranges => 1.1 GB spill).

#define KK 9
#define PAD 1
#define H 512
#define W 512
#define HW (H * W)

#define TX 64
#define TY 8
#define HALO 8
#define LW (TX + 2 * HALO)   // 80
#define LH (TY + 2 * HALO)   // 24

typedef float f2 __attribute__((ext_vector_type(2)));

__device__ __forceinline__ float bilin_global(const float* __restrict__ img,
                                              float y, float x) {
    float y0f = floorf(y);
    float x0f = floorf(x);
    int y0 = (int)y0f;
    int x0 = (int)x0f;
    float wy = y - y0f;
    float wx = x - x0f;
    int y1 = y0 + 1;
    int x1 = x0 + 1;

    bool y0i = (y0 >= 0) & (y0 < H);
    bool y1i = (y1 >= 0) & (y1 < H);
    bool x0i = (x0 >= 0) & (x0 < W);
    bool x1i = (x1 >= 0) & (x1 < W);

    int y0c = min(max(y0, 0), H - 1);
    int y1c = min(max(y1, 0), H - 1);
    int x0c = min(max(x0, 0), W - 1);
    int x1c = min(max(x1, 0), W - 1);

    float v00 = (y0i & x0i) ? img[y0c * W + x0c] : 0.0f;
    float v01 = (y0i & x1i) ? img[y0c * W + x1c] : 0.0f;
    float v10 = (y1i & x0i) ? img[y1c * W + x0c] : 0.0f;
    float v11 = (y1i & x1i) ? img[y1c * W + x1c] : 0.0f;

    float omwy = 1.0f - wy;
    float omwx = 1.0f - wx;
    return fmaf(v00 * omwy, omwx,
           fmaf(v01 * omwy, wx,
           fmaf(v10 * wy,   omwx, v11 * wy * wx)));
}

__device__ __forceinline__ float sample_tile(const float* __restrict__ S,
                                             const float* __restrict__ img,
                                             int tY0, int tX0,
                                             float sy, float sx) {
    const float y0f = floorf(sy);
    const float x0f = floorf(sx);
    const float wy = sy - y0f;
    const float wx = sx - x0f;
    const int ly0 = (int)y0f - tY0;
    const int lx0 = (int)x0f - tX0;

    if (((unsigned)ly0 < (unsigned)(LH - 1)) &
        ((unsigned)lx0 < (unsigned)(LW - 1))) {
        const int s = ly0 * LW + lx0;
        const float v00 = S[s];
        const float v01 = S[s + 1];
        const float v10 = S[s + LW];
        const float v11 = S[s + LW + 1];
        const float omwy = 1.0f - wy;
        const float omwx = 1.0f - wx;
        return fmaf(v00 * omwy, omwx,
               fmaf(v01 * omwy, wx,
               fmaf(v10 * wy,   omwx, v11 * wy * wx)));
    }
    // ~never taken (|offset| >= ~7, p ~ 2.6e-12/sample): correct global fallback
    return bilin_global(img, sy, sx);
}

__global__ void dcn_kernel(
    const float* __restrict__ depth,
    const float* __restrict__ mask,
    const float* __restrict__ offset,
    const float* __restrict__ w9,
    const float* __restrict__ bias,
    float* __restrict__ out) {
    __shared__ float S[LH * LW];

    const int b  = blockIdx.z;
    const int bx = blockIdx.x;
    const int by = blockIdx.y;
    const int tX0 = bx * TX - HALO;
    const int tY0 = by * TY - HALO;

    const float* __restrict__ img = depth + (long)b * HW;

    // --- stage depth tile (+halo) into LDS; out-of-image cells = 0 ---
    for (int i = threadIdx.x; i < LH * LW; i += 256) {
        const int ly = i / LW;
        const int lx = i - ly * LW;
        const int gy = tY0 + ly;
        const int gx = tX0 + lx;
        float v = 0.0f;
        if (((unsigned)gy < (unsigned)H) & ((unsigned)gx < (unsigned)W))
            v = img[gy * W + gx];
        S[i] = v;
    }
    __syncthreads();

    // --- 2 consecutive px/thread; all 27 streaming dwordx2 loads up front ---
    const int xp = threadIdx.x & 31;        // x-pair 0..31
    const int yr = threadIdx.x >> 5;        // row 0..7
    const int tx = bx * TX + 2 * xp;
    const int ty = by * TY + yr;
    const int pix = ty * W + tx;

    const float* __restrict__ msk = mask   + ((long)b * KK)     * HW + pix;
    const float* __restrict__ off = offset + ((long)b * 2 * KK) * HW + pix;

    f2 dyv[KK], dxv[KK], mv[KK];
    #pragma unroll
    for (int k = 0; k < KK; ++k) {
        dyv[k] = *(const f2*)(off + (2 * k) * HW);
        dxv[k] = *(const f2*)(off + (2 * k + 1) * HW);
        mv[k]  = *(const f2*)(msk + k * HW);
    }

    const float bs = bias[0];
    float a0 = bs, a1 = bs;
    const float syb = (float)(ty - PAD);
    const float sxb = (float)(tx - PAD);

    #pragma unroll
    for (int k = 0; k < KK; ++k) {
        const int ky = k / 3;
        const int kx = k - ky * 3;
        const float wk = w9[k];
        const float sy = syb + (float)ky;
        const float sx = sxb + (float)kx;

        a0 = fmaf(sample_tile(S, img, tY0, tX0, sy + dyv[k].x, sx + 0.0f + dxv[k].x),
                  mv[k].x * wk, a0);
        a1 = fmaf(sample_tile(S, img, tY0, tX0, sy + dyv[k].y, sx + 1.0f + dxv[k].y),
                  mv[k].y * wk, a1);
    }

    f2 r; r.x = a0; r.y = a1;
    *(f2*)(out + (long)b * HW + pix) = r;
}

extern "C" void kernel_launch(void* const* d_in, const int* in_sizes, int n_in,
                              void* d_out, int out_size, void* d_ws, size_t ws_size,
                              hipStream_t stream) {
    const float* depth  = (const float*)d_in[0];
    const float* mask   = (const float*)d_in[1];   // reference's "weight" arg = modulation mask
    const float* offset = (const float*)d_in[2];
    const float* w9     = (const float*)d_in[3];
    const float* bias   = (const float*)d_in[4];
    float* out = (float*)d_out;

    const int B = in_sizes[0] / HW;   // = 8

    dim3 block(256);
    dim3 grid(W / TX, H / TY, B);     // (8, 64, 8)
    dcn_kernel<<<grid, block, 0, stream>>>(depth, mask, offset, w9, bias, out);
}

// Round 6
// 274.404 us; speedup vs baseline: 2.2996x; 1.0095x over previous
//
#include <hip/hip_runtime.h>

// Modulated deformable conv 3x3, in_ch=out_ch=1, stride=1, pad=1, dil=1.
// B=8, H=W=512. d_in order: depth, mask(weight), offset, w, b.
// R6 = R5 + sched_barrier(0) fence between the 27-load batch and consumption.
// R5 post-mortem: VGPR_Count=40 proved the scheduler sank the upfront loads
// back to their uses (54-float payload can't fit in 40 VGPRs) -> MLP never
// materialized. The fence forces all 27 dwordx2 streaming loads in flight
// per wave, consumed with progressive vmcnt waits.
// LDS depth tile 64x8 out + halo 8 (7.7 KB); rare global fallback for |off|>=~7.

#define KK 9
#define PAD 1
#define H 512
#define W 512
#define HW (H * W)

#define TX 64
#define TY 8
#define HALO 8
#define LW (TX + 2 * HALO)   // 80
#define LH (TY + 2 * HALO)   // 24

typedef float f2 __attribute__((ext_vector_type(2)));

__device__ __forceinline__ float bilin_global(const float* __restrict__ img,
                                              float y, float x) {
    float y0f = floorf(y);
    float x0f = floorf(x);
    int y0 = (int)y0f;
    int x0 = (int)x0f;
    float wy = y - y0f;
    float wx = x - x0f;
    int y1 = y0 + 1;
    int x1 = x0 + 1;

    bool y0i = (y0 >= 0) & (y0 < H);
    bool y1i = (y1 >= 0) & (y1 < H);
    bool x0i = (x0 >= 0) & (x0 < W);
    bool x1i = (x1 >= 0) & (x1 < W);

    int y0c = min(max(y0, 0), H - 1);
    int y1c = min(max(y1, 0), H - 1);
    int x0c = min(max(x0, 0), W - 1);
    int x1c = min(max(x1, 0), W - 1);

    float v00 = (y0i & x0i) ? img[y0c * W + x0c] : 0.0f;
    float v01 = (y0i & x1i) ? img[y0c * W + x1c] : 0.0f;
    float v10 = (y1i & x0i) ? img[y1c * W + x0c] : 0.0f;
    float v11 = (y1i & x1i) ? img[y1c * W + x1c] : 0.0f;

    float omwy = 1.0f - wy;
    float omwx = 1.0f - wx;
    return fmaf(v00 * omwy, omwx,
           fmaf(v01 * omwy, wx,
           fmaf(v10 * wy,   omwx, v11 * wy * wx)));
}

__device__ __forceinline__ float sample_tile(const float* __restrict__ S,
                                             const float* __restrict__ img,
                                             int tY0, int tX0,
                                             float sy, float sx) {
    const float y0f = floorf(sy);
    const float x0f = floorf(sx);
    const float wy = sy - y0f;
    const float wx = sx - x0f;
    const int ly0 = (int)y0f - tY0;
    const int lx0 = (int)x0f - tX0;

    if (((unsigned)ly0 < (unsigned)(LH - 1)) &
        ((unsigned)lx0 < (unsigned)(LW - 1))) {
        const int s = ly0 * LW + lx0;
        const float v00 = S[s];
        const float v01 = S[s + 1];
        const float v10 = S[s + LW];
        const float v11 = S[s + LW + 1];
        const float omwy = 1.0f - wy;
        const float omwx = 1.0f - wx;
        return fmaf(v00 * omwy, omwx,
               fmaf(v01 * omwy, wx,
               fmaf(v10 * wy,   omwx, v11 * wy * wx)));
    }
    // ~never taken (|offset| >= ~7, p ~ 2.6e-12/sample): correct global fallback
    return bilin_global(img, sy, sx);
}

__global__ void dcn_kernel(
    const float* __restrict__ depth,
    const float* __restrict__ mask,
    const float* __restrict__ offset,
    const float* __restrict__ w9,
    const float* __restrict__ bias,
    float* __restrict__ out) {
    __shared__ float S[LH * LW];

    const int b  = blockIdx.z;
    const int bx = blockIdx.x;
    const int by = blockIdx.y;
    const int tX0 = bx * TX - HALO;
    const int tY0 = by * TY - HALO;

    const float* __restrict__ img = depth + (long)b * HW;

    // --- stage depth tile (+halo) into LDS; out-of-image cells = 0 ---
    for (int i = threadIdx.x; i < LH * LW; i += 256) {
        const int ly = i / LW;
        const int lx = i - ly * LW;
        const int gy = tY0 + ly;
        const int gx = tX0 + lx;
        float v = 0.0f;
        if (((unsigned)gy < (unsigned)H) & ((unsigned)gx < (unsigned)W))
            v = img[gy * W + gx];
        S[i] = v;
    }
    __syncthreads();

    // --- 2 consecutive px/thread; all 27 streaming dwordx2 loads up front ---
    const int xp = threadIdx.x & 31;        // x-pair 0..31
    const int yr = threadIdx.x >> 5;        // row 0..7
    const int tx = bx * TX + 2 * xp;
    const int ty = by * TY + yr;
    const int pix = ty * W + tx;

    const float* __restrict__ msk = mask   + ((long)b * KK)     * HW + pix;
    const float* __restrict__ off = offset + ((long)b * 2 * KK) * HW + pix;

    f2 dyv[KK], dxv[KK], mv[KK];
    #pragma unroll
    for (int k = 0; k < KK; ++k) {
        dyv[k] = *(const f2*)(off + (2 * k) * HW);
        dxv[k] = *(const f2*)(off + (2 * k + 1) * HW);
        mv[k]  = *(const f2*)(msk + k * HW);
    }

    // Fence: nothing crosses. Forces all 27 loads issued before any consume,
    // i.e. 27 outstanding vmem ops/wave with progressive vmcnt consumption.
    __builtin_amdgcn_sched_barrier(0);

    const float bs = bias[0];
    float a0 = bs, a1 = bs;
    const float syb = (float)(ty - PAD);
    const float sxb = (float)(tx - PAD);

    #pragma unroll
    for (int k = 0; k < KK; ++k) {
        const int ky = k / 3;
        const int kx = k - ky * 3;
        const float wk = w9[k];
        const float sy = syb + (float)ky;
        const float sx = sxb + (float)kx;

        a0 = fmaf(sample_tile(S, img, tY0, tX0, sy + dyv[k].x, sx + 0.0f + dxv[k].x),
                  mv[k].x * wk, a0);
        a1 = fmaf(sample_tile(S, img, tY0, tX0, sy + dyv[k].y, sx + 1.0f + dxv[k].y),
                  mv[k].y * wk, a1);
    }

    f2 r; r.x = a0; r.y = a1;
    *(f2*)(out + (long)b * HW + pix) = r;
}

extern "C" void kernel_launch(void* const* d_in, const int* in_sizes, int n_in,
                              void* d_out, int out_size, void* d_ws, size_t ws_size,
                              hipStream_t stream) {
    const float* depth  = (const float*)d_in[0];
    const float* mask   = (const float*)d_in[1];   // reference's "weight" arg = modulation mask
    const float* offset = (const float*)d_in[2];
    const float* w9     = (const float*)d_in[3];
    const float* bias   = (const float*)d_in[4];
    float* out = (float*)d_out;

    const int B = in_sizes[0] / HW;   // = 8

    dim3 block(256);
    dim3 grid(W / TX, H / TY, B);     // (8, 64, 8)
    dcn_kernel<<<grid, block, 0, stream>>>(depth, mask, offset, w9, bias, out);
}